// Round 5
// baseline (3879.300 us; speedup 1.0000x reference)
//
#include <hip/hip_runtime.h>
#include <cstdint>

// ---------------------------------------------------------------------------
#define BATCH   16
#define T_IN    2048
#define HID1    512
#define HID2    1024
#define T1      1024
#define T2      512
#define CODE_DIM 512
#define N_TOK   8192
#define N_RES   3
#define N_ROWS  (BATCH * T2)

typedef short bf16x8 __attribute__((ext_vector_type(8)));
typedef float f32x4  __attribute__((ext_vector_type(4)));
typedef unsigned short u16;

union B128 { int4 i; bf16x8 b; };

// bf16x2 split: u32 = hi_bits | (lo_bits << 16); v ~= bf16(hi) + bf16(lo)
__device__ __forceinline__ unsigned splitpack(float v) {
    unsigned r  = __float_as_uint(v);
    unsigned hi = (r + 0x7FFFu + ((r >> 16) & 1u)) >> 16;
    float    res = v - __uint_as_float(hi << 16);
    unsigned rl = __float_as_uint(res);
    unsigned lo = (rl + 0x7FFFu + ((rl >> 16) & 1u)) >> 16;
    return hi | (lo << 16);
}
__device__ __forceinline__ float bf2f(u16 b) { return __uint_as_float(((unsigned)b) << 16); }
__device__ __forceinline__ int swz(int row) { return (row ^ (row >> 2)) & 3; }

// ---------------------------------------------------------------------------
// Round-5 conv: merged-tap single staging phase + reg-prefetch (T14) + setprio.
// Block BM=2*WR rows x BN=128 cols, 4 waves 2x2, wave tile WR x 64.
// Loop per c0 (K=32): [barrier; ds_write staged regs; barrier; issue loads
// for c0+32; MFMA over 3 taps x 3 split-passes]. Requires pre-split W planes
// [tap][O][Cin] (WPRE path only).
// ---------------------------------------------------------------------------
template<int TAPS, int S, int WR, bool RELU, bool ADD>
__global__ __launch_bounds__(256, 2)
void conv_mfma2(const u16* __restrict__ xH, const u16* __restrict__ xL,
                const u16* __restrict__ wHp, const u16* __restrict__ wLp,
                const float* __restrict__ bias,
                const u16* __restrict__ addH, const u16* __restrict__ addL,
                u16* __restrict__ oH, u16* __restrict__ oL,
                int Cin, int Cout, int Tin, int Tout, int ntc)
{
    constexpr int BM = WR * 2, BN = 128;
    constexpr int PAD  = (TAPS == 3) ? 1 : 0;
    constexpr int SPAN = BM * S + TAPS - S;     // <= 256 for all instantiations
    constexpr int MF   = WR / 16;
    static_assert(SPAN <= 256, "one staged row per thread");

    __shared__ int4 sXh[SPAN][4], sXl[SPAN][4];
    __shared__ int4 sWh[TAPS][BN][4], sWl[TAPS][BN][4];

    const int tid  = threadIdx.x;
    const int lane = tid & 63, wid = tid >> 6;
    const int wm = wid >> 1, wn = wid & 1;
    const int l15 = lane & 15, l4 = lane >> 4;

    const int bid = blockIdx.x;
    const int nt = bid % ntc, mt = bid / ntc;   // same-nt blocks cluster on XCD (rr)
    const int R0 = mt * BM, o0 = nt * BN;
    const int b  = R0 / Tout, t0 = R0 % Tout;
    const int tbase = t0 * S - PAD;

    const u16* bxH = xH + (size_t)b * Tin * Cin;
    const u16* bxL = xL + (size_t)b * Tin * Cin;

    f32x4 acc[MF][4] = {};

    // prefetch registers
    int4 pXh[4], pXl[4], pW[TAPS][4];
    const int  xt     = tbase + tid;
    const bool xvalid = (tid < SPAN) && (xt >= 0) && (xt < Tin);
    const int  wrow   = tid >> 1, whalf = tid & 1;

    auto loadX = [&](int c0) {
        if (xvalid) {
            const int4* pH = (const int4*)(bxH + (size_t)xt * Cin + c0);
            const int4* pL = (const int4*)(bxL + (size_t)xt * Cin + c0);
#pragma unroll
            for (int j = 0; j < 4; ++j) { pXh[j] = pH[j]; pXl[j] = pL[j]; }
        } else {
            const int4 z = {0, 0, 0, 0};
#pragma unroll
            for (int j = 0; j < 4; ++j) { pXh[j] = z; pXl[j] = z; }
        }
    };
    auto loadW = [&](int c0) {
#pragma unroll
        for (int u = 0; u < TAPS; ++u) {
            const size_t base = ((size_t)u * Cout + (o0 + wrow)) * Cin + c0 + whalf * 16;
            const int4* pH = (const int4*)(wHp + base);
            const int4* pL = (const int4*)(wLp + base);
            pW[u][0] = pH[0]; pW[u][1] = pH[1];
            pW[u][2] = pL[0]; pW[u][3] = pL[1];
        }
    };
    auto storeLDS = [&]() {
        if (tid < SPAN) {
            const int s = swz(tid);
#pragma unroll
            for (int j = 0; j < 4; ++j) sXh[tid][j ^ s] = pXh[j];
#pragma unroll
            for (int j = 0; j < 4; ++j) sXl[tid][j ^ s] = pXl[j];
        }
        const int s = swz(wrow);
#pragma unroll
        for (int u = 0; u < TAPS; ++u) {
            sWh[u][wrow][(whalf * 2 + 0) ^ s] = pW[u][0];
            sWh[u][wrow][(whalf * 2 + 1) ^ s] = pW[u][1];
            sWl[u][wrow][(whalf * 2 + 0) ^ s] = pW[u][2];
            sWl[u][wrow][(whalf * 2 + 1) ^ s] = pW[u][3];
        }
    };

    loadX(0); loadW(0);
    for (int c0 = 0; c0 < Cin; c0 += 32) {
        __syncthreads();          // previous MFMA phase done reading LDS
        storeLDS();
        __syncthreads();
        if (c0 + 32 < Cin) { loadX(c0 + 32); loadW(c0 + 32); }   // hide under MFMA

        __builtin_amdgcn_s_setprio(1);
#pragma unroll
        for (int tap = 0; tap < TAPS; ++tap) {
            B128 bh[4], bl[4];
#pragma unroll
            for (int nf = 0; nf < 4; ++nf) {
                const int orow = wn * 64 + nf * 16 + l15;
                const int sl = l4 ^ swz(orow);
                bh[nf].i = sWh[tap][orow][sl];
                bl[nf].i = sWl[tap][orow][sl];
            }
#pragma unroll
            for (int mf = 0; mf < MF; ++mf) {
                const int r = (wm * WR + mf * 16 + l15) * S + tap;
                const int sl = l4 ^ swz(r);
                B128 ah, al;
                ah.i = sXh[r][sl];  al.i = sXl[r][sl];
#pragma unroll
                for (int nf = 0; nf < 4; ++nf) {
                    acc[mf][nf] = __builtin_amdgcn_mfma_f32_16x16x32_bf16(ah.b, bh[nf].b, acc[mf][nf], 0, 0, 0);
                    acc[mf][nf] = __builtin_amdgcn_mfma_f32_16x16x32_bf16(ah.b, bl[nf].b, acc[mf][nf], 0, 0, 0);
                    acc[mf][nf] = __builtin_amdgcn_mfma_f32_16x16x32_bf16(al.b, bh[nf].b, acc[mf][nf], 0, 0, 0);
                }
            }
        }
        __builtin_amdgcn_s_setprio(0);
    }

    // epilogue: D row=(l>>4)*4+rg (t), col=l&15 (o)
#pragma unroll
    for (int nf = 0; nf < 4; ++nf) {
        const int o = o0 + wn * 64 + nf * 16 + l15;
        const float bv = bias[o];
#pragma unroll
        for (int mf = 0; mf < MF; ++mf) {
#pragma unroll
            for (int rg = 0; rg < 4; ++rg) {
                const int Rl = wm * WR + mf * 16 + l4 * 4 + rg;
                const size_t idx = (size_t)(R0 + Rl) * Cout + o;
                float v = acc[mf][nf][rg] + bv;
                if constexpr (ADD)  v += bf2f(addH[idx]) + bf2f(addL[idx]);
                if constexpr (RELU) v = fmaxf(v, 0.f);
                const unsigned p = splitpack(v);
                oH[idx] = (u16)(p & 0xFFFFu);
                oL[idx] = (u16)(p >> 16);
            }
        }
    }
}

// ---------------------------------------------------------------------------
// Round-4 conv kernel, kept VERBATIM as the ws-too-small fallback path.
// ---------------------------------------------------------------------------
template<int TAPS, int S, int WR, bool WPRE, bool RELU, bool ADD>
__global__ __launch_bounds__(256, 2)
void conv_mfma(const u16* __restrict__ xH, const u16* __restrict__ xL,
               const float* __restrict__ wraw,
               const u16* __restrict__ wHp, const u16* __restrict__ wLp,
               const float* __restrict__ bias,
               const u16* __restrict__ addH, const u16* __restrict__ addL,
               u16* __restrict__ oH, u16* __restrict__ oL,
               int Cin, int Cout, int Tin, int Tout, int ntc)
{
    constexpr int BM = WR * 2, BN = 128;
    constexpr int PAD  = (TAPS == 3) ? 1 : 0;
    constexpr int SPAN = BM * S + TAPS - S;
    constexpr int MF   = WR / 16;

    __shared__ int4 sXh[SPAN][4], sXl[SPAN][4];
    __shared__ int4 sWh[BN][4],  sWl[BN][4];

    const int tid  = threadIdx.x;
    const int lane = tid & 63, wid = tid >> 6;
    const int wm = wid >> 1, wn = wid & 1;
    const int l15 = lane & 15, l4 = lane >> 4;

    const int bid = blockIdx.x;
    const int nt = bid % ntc, mt = bid / ntc;
    const int R0 = mt * BM, o0 = nt * BN;
    const int b  = R0 / Tout, t0 = R0 % Tout;
    const int tbase = t0 * S - PAD;

    f32x4 acc[MF][4] = {};

    const u16* bxH = xH + (size_t)b * Tin * Cin;
    const u16* bxL = xL + (size_t)b * Tin * Cin;

    for (int c0 = 0; c0 < Cin; c0 += 32) {
        for (int tap = 0; tap < TAPS; ++tap) {
            __syncthreads();
            if (tap == 0) {
                for (int r = tid; r < SPAN; r += 256) {
                    const int t = tbase + r;
                    const int s = swz(r);
                    if (t >= 0 && t < Tin) {
                        const int4* pH = (const int4*)(bxH + (size_t)t * Cin + c0);
                        const int4* pL = (const int4*)(bxL + (size_t)t * Cin + c0);
#pragma unroll
                        for (int j = 0; j < 4; ++j) sXh[r][j ^ s] = pH[j];
#pragma unroll
                        for (int j = 0; j < 4; ++j) sXl[r][j ^ s] = pL[j];
                    } else {
                        const int4 z = {0, 0, 0, 0};
#pragma unroll
                        for (int j = 0; j < 4; ++j) { sXh[r][j] = z; sXl[r][j] = z; }
                    }
                }
            }
            if constexpr (WPRE) {
                const int row = tid & 127, half = tid >> 7;
                const int s = swz(row);
                const size_t base = ((size_t)tap * Cout + (o0 + row)) * Cin + c0 + half * 16;
                const int4* pH = (const int4*)(wHp + base);
                const int4* pL = (const int4*)(wLp + base);
                sWh[row][(half * 2 + 0) ^ s] = pH[0];
                sWh[row][(half * 2 + 1) ^ s] = pH[1];
                sWl[row][(half * 2 + 0) ^ s] = pL[0];
                sWl[row][(half * 2 + 1) ^ s] = pL[1];
            } else {
                const int row = tid >> 1, half = tid & 1;
                const int s = swz(row);
                const float* wp = wraw + ((size_t)(o0 + row) * Cin + (c0 + half * 16)) * TAPS + tap;
                unsigned p[16];
#pragma unroll
                for (int j = 0; j < 16; ++j) p[j] = splitpack(wp[(size_t)j * TAPS]);
                int4 h0, h1, l0, l1;
                h0.x = (int)((p[0]&0xFFFFu)|(p[1]<<16));   h0.y = (int)((p[2]&0xFFFFu)|(p[3]<<16));
                h0.z = (int)((p[4]&0xFFFFu)|(p[5]<<16));   h0.w = (int)((p[6]&0xFFFFu)|(p[7]<<16));
                h1.x = (int)((p[8]&0xFFFFu)|(p[9]<<16));   h1.y = (int)((p[10]&0xFFFFu)|(p[11]<<16));
                h1.z = (int)((p[12]&0xFFFFu)|(p[13]<<16)); h1.w = (int)((p[14]&0xFFFFu)|(p[15]<<16));
                l0.x = (int)((p[0]>>16)|(p[1]&0xFFFF0000u));   l0.y = (int)((p[2]>>16)|(p[3]&0xFFFF0000u));
                l0.z = (int)((p[4]>>16)|(p[5]&0xFFFF0000u));   l0.w = (int)((p[6]>>16)|(p[7]&0xFFFF0000u));
                l1.x = (int)((p[8]>>16)|(p[9]&0xFFFF0000u));   l1.y = (int)((p[10]>>16)|(p[11]&0xFFFF0000u));
                l1.z = (int)((p[12]>>16)|(p[13]&0xFFFF0000u)); l1.w = (int)((p[14]>>16)|(p[15]&0xFFFF0000u));
                sWh[row][(half * 2 + 0) ^ s] = h0;  sWh[row][(half * 2 + 1) ^ s] = h1;
                sWl[row][(half * 2 + 0) ^ s] = l0;  sWl[row][(half * 2 + 1) ^ s] = l1;
            }
            __syncthreads();

            B128 bh[4], bl[4];
#pragma unroll
            for (int nf = 0; nf < 4; ++nf) {
                const int orow = wn * 64 + nf * 16 + l15;
                const int sl = l4 ^ swz(orow);
                bh[nf].i = sWh[orow][sl];  bl[nf].i = sWl[orow][sl];
            }
#pragma unroll
            for (int mf = 0; mf < MF; ++mf) {
                const int r = (wm * WR + mf * 16 + l15) * S + tap;
                const int sl = l4 ^ swz(r);
                B128 ah, al;
                ah.i = sXh[r][sl];  al.i = sXl[r][sl];
#pragma unroll
                for (int nf = 0; nf < 4; ++nf) {
                    acc[mf][nf] = __builtin_amdgcn_mfma_f32_16x16x32_bf16(ah.b, bh[nf].b, acc[mf][nf], 0, 0, 0);
                    acc[mf][nf] = __builtin_amdgcn_mfma_f32_16x16x32_bf16(ah.b, bl[nf].b, acc[mf][nf], 0, 0, 0);
                    acc[mf][nf] = __builtin_amdgcn_mfma_f32_16x16x32_bf16(al.b, bh[nf].b, acc[mf][nf], 0, 0, 0);
                }
            }
        }
    }

#pragma unroll
    for (int nf = 0; nf < 4; ++nf) {
        const int o = o0 + wn * 64 + nf * 16 + l15;
        const float bv = bias[o];
#pragma unroll
        for (int mf = 0; mf < MF; ++mf) {
#pragma unroll
            for (int rg = 0; rg < 4; ++rg) {
                const int Rl = wm * WR + mf * 16 + l4 * 4 + rg;
                const size_t idx = (size_t)(R0 + Rl) * Cout + o;
                float v = acc[mf][nf][rg] + bv;
                if constexpr (ADD)  v += bf2f(addH[idx]) + bf2f(addL[idx]);
                if constexpr (RELU) v = fmaxf(v, 0.f);
                const unsigned p = splitpack(v);
                oH[idx] = (u16)(p & 0xFFFFu);
                oL[idx] = (u16)(p >> 16);
            }
        }
    }
}

// ---------------------------------------------------------------------------
// Prep kernels
// ---------------------------------------------------------------------------
__global__ void prep_x(const float* __restrict__ x, u16* __restrict__ xH, u16* __restrict__ xL)
{
    const int id = blockIdx.x * 256 + threadIdx.x;     // (b,t)
    const int b = id >> 11, t = id & 2047;
    const float* src = x + (size_t)b * 80 * 2048 + t;
    u16* dH = xH + (size_t)id * 96;
    u16* dL = xL + (size_t)id * 96;
    for (int c = 0; c < 96; ++c) {
        const float v = (c < 80) ? src[(size_t)c * 2048] : 0.f;
        const unsigned p = splitpack(v);
        dH[c] = (u16)(p & 0xFFFFu);
        dL[c] = (u16)(p >> 16);
    }
}

// w fp32 [O][CinR][TAPS] -> planes [TAPS][O][CinP] (c >= CinR zero-padded)
__global__ void prep_w(const float* __restrict__ w, u16* __restrict__ wH, u16* __restrict__ wL,
                       int O, int CinR, int CinP, int TAPS)
{
    const int id = blockIdx.x * 256 + threadIdx.x;     // (o, c) over CinP
    if (id >= O * CinP) return;
    const int o = id / CinP, c = id % CinP;
    for (int t = 0; t < TAPS; ++t) {
        const float v = (c < CinR) ? w[((size_t)o * CinR + c) * TAPS + t] : 0.f;
        const unsigned p = splitpack(v);
        const size_t dst = ((size_t)t * O + o) * CinP + c;
        wH[dst] = (u16)(p & 0xFFFFu);
        wL[dst] = (u16)(p >> 16);
    }
}

__global__ void prep_cb(const float* __restrict__ cb, u16* __restrict__ cH, u16* __restrict__ cL)
{
    __shared__ float tile[32][33];
    const int jb = blockIdx.x * 32, db = blockIdx.y * 32;
    const int c = threadIdx.x & 31, r = threadIdx.x >> 5;
    for (int rr = r; rr < 32; rr += 8)
        tile[rr][c] = cb[(size_t)(db + rr) * N_TOK + jb + c];
    __syncthreads();
    for (int rr = r; rr < 32; rr += 8) {
        const unsigned p = splitpack(tile[c][rr]);
        const size_t dst = (size_t)(jb + rr) * CODE_DIM + db + c;
        cH[dst] = (u16)(p & 0xFFFFu);
        cL[dst] = (u16)(p >> 16);
    }
}

__global__ void cnorm_kernel(const float* __restrict__ cb, float* __restrict__ cnorm)
{
    const int j = blockIdx.x * 256 + threadIdx.x;
    float s = 0.f;
#pragma unroll 8
    for (int d = 0; d < CODE_DIM; ++d) {
        const float v = cb[(size_t)d * N_TOK + j];
        s += v * v;
    }
    cnorm[j] = s;
}

// ---------------------------------------------------------------------------
// VQ: argmax_j (2*f.c_j - |c_j|^2), MFMA, now with reg-prefetch + setprio.
// Block 256 rows x 128 codes, 4 waves 2x2 (wave 128 rows x 64 codes).
// ---------------------------------------------------------------------------
__global__ __launch_bounds__(256, 2)
void vq_mfma(const u16* __restrict__ latH, const u16* __restrict__ latL,
             const u16* __restrict__ cbH, const u16* __restrict__ cbL,
             const float* __restrict__ cnorm,
             float* __restrict__ pval, int* __restrict__ pidx)
{
    __shared__ int4 sXh[256][4], sXl[256][4];
    __shared__ int4 sWh[128][4], sWl[128][4];

    const int tid  = threadIdx.x;
    const int lane = tid & 63, wid = tid >> 6;
    const int wm = wid >> 1, wn = wid & 1;
    const int l15 = lane & 15, l4 = lane >> 4;
    const int R0 = blockIdx.x * 256;
    const int o0 = blockIdx.y * 128;

    f32x4 acc[8][4] = {};

    int4 pXh[4], pXl[4], pW[4];
    const u16* xrowH = latH + (size_t)(R0 + tid) * CODE_DIM;
    const u16* xrowL = latL + (size_t)(R0 + tid) * CODE_DIM;
    const int wrow = tid >> 1, whalf = tid & 1;
    const u16* wrowH = cbH + (size_t)(o0 + wrow) * CODE_DIM + whalf * 16;
    const u16* wrowL = cbL + (size_t)(o0 + wrow) * CODE_DIM + whalf * 16;

    auto loadAll = [&](int c0) {
        const int4* pH = (const int4*)(xrowH + c0);
        const int4* pL = (const int4*)(xrowL + c0);
#pragma unroll
        for (int j = 0; j < 4; ++j) { pXh[j] = pH[j]; pXl[j] = pL[j]; }
        pW[0] = ((const int4*)(wrowH + c0))[0];
        pW[1] = ((const int4*)(wrowH + c0))[1];
        pW[2] = ((const int4*)(wrowL + c0))[0];
        pW[3] = ((const int4*)(wrowL + c0))[1];
    };
    auto storeLDS = [&]() {
        const int s = swz(tid);
#pragma unroll
        for (int j = 0; j < 4; ++j) sXh[tid][j ^ s] = pXh[j];
#pragma unroll
        for (int j = 0; j < 4; ++j) sXl[tid][j ^ s] = pXl[j];
        const int ws = swz(wrow);
        sWh[wrow][(whalf * 2 + 0) ^ ws] = pW[0];
        sWh[wrow][(whalf * 2 + 1) ^ ws] = pW[1];
        sWl[wrow][(whalf * 2 + 0) ^ ws] = pW[2];
        sWl[wrow][(whalf * 2 + 1) ^ ws] = pW[3];
    };

    loadAll(0);
    for (int c0 = 0; c0 < CODE_DIM; c0 += 32) {
        __syncthreads();
        storeLDS();
        __syncthreads();
        if (c0 + 32 < CODE_DIM) loadAll(c0 + 32);

        __builtin_amdgcn_s_setprio(1);
        B128 bh[4], bl[4];
#pragma unroll
        for (int nf = 0; nf < 4; ++nf) {
            const int orow = wn * 64 + nf * 16 + l15;
            const int sl = l4 ^ swz(orow);
            bh[nf].i = sWh[orow][sl];  bl[nf].i = sWl[orow][sl];
        }
#pragma unroll
        for (int mf = 0; mf < 8; ++mf) {
            const int r = wm * 128 + mf * 16 + l15;
            const int sl = l4 ^ swz(r);
            B128 ah, al;
            ah.i = sXh[r][sl];  al.i = sXl[r][sl];
#pragma unroll
            for (int nf = 0; nf < 4; ++nf) {
                acc[mf][nf] = __builtin_amdgcn_mfma_f32_16x16x32_bf16(ah.b, bh[nf].b, acc[mf][nf], 0, 0, 0);
                acc[mf][nf] = __builtin_amdgcn_mfma_f32_16x16x32_bf16(ah.b, bl[nf].b, acc[mf][nf], 0, 0, 0);
                acc[mf][nf] = __builtin_amdgcn_mfma_f32_16x16x32_bf16(al.b, bh[nf].b, acc[mf][nf], 0, 0, 0);
            }
        }
        __builtin_amdgcn_s_setprio(0);
    }

    float cn[4]; int jb[4];
#pragma unroll
    for (int nf = 0; nf < 4; ++nf) {
        jb[nf] = o0 + wn * 64 + nf * 16 + l15;
        cn[nf] = cnorm[jb[nf]];
    }
    const int slice = blockIdx.y * 2 + wn;
#pragma unroll
    for (int mf = 0; mf < 8; ++mf) {
#pragma unroll
        for (int rg = 0; rg < 4; ++rg) {
            float bv = -3.4e38f; int bj = 0;
#pragma unroll
            for (int nf = 0; nf < 4; ++nf) {      // ascending j: strict > keeps first min
                const float v = 2.f * acc[mf][nf][rg] - cn[nf];
                if (v > bv) { bv = v; bj = jb[nf]; }
            }
#pragma unroll
            for (int m = 1; m < 16; m <<= 1) {
                const float ov = __shfl_xor(bv, m, 64);
                const int   oj = __shfl_xor(bj, m, 64);
                if (ov > bv || (ov == bv && oj < bj)) { bv = ov; bj = oj; }
            }
            if (l15 == 0) {
                const int R = R0 + wm * 128 + mf * 16 + l4 * 4 + rg;
                pval[(size_t)slice * N_ROWS + R] = bv;
                pidx[(size_t)slice * N_ROWS + R] = bj;
            }
        }
    }
}

__global__ void vq_merge(const float* __restrict__ pval, const int* __restrict__ pidx,
                         int* __restrict__ out)
{
    const int row = blockIdx.x * 256 + threadIdx.x;
    float bv = pval[row]; int bj = pidx[row];
    for (int s = 1; s < 128; ++s) {
        const float v = pval[(size_t)s * N_ROWS + row];
        const int   j = pidx[(size_t)s * N_ROWS + row];
        if (v > bv || (v == bv && j < bj)) { bv = v; bj = j; }
    }
    out[row] = bj;
}

// ---------------------------------------------------------------------------
// Launch
// ---------------------------------------------------------------------------
extern "C" void kernel_launch(void* const* d_in, const int* in_sizes, int n_in,
                              void* d_out, int out_size, void* d_ws, size_t ws_size,
                              hipStream_t stream)
{
    const float* x   = (const float*)d_in[0];
    const float* w1  = (const float*)d_in[1];
    const float* b1  = (const float*)d_in[2];
    const float* w2  = (const float*)d_in[3];
    const float* b2  = (const float*)d_in[4];
    const float* rwa = (const float*)d_in[5];
    const float* rba = (const float*)d_in[6];
    const float* rwb = (const float*)d_in[7];
    const float* rbb = (const float*)d_in[8];
    const float* rwc = (const float*)d_in[9];
    const float* rbc = (const float*)d_in[10];
    const float* wf  = (const float*)d_in[11];
    const float* bf  = (const float*)d_in[12];
    const float* cb  = (const float*)d_in[13];

    char* W = (char*)d_ws;
    // byte layout (base 100.66MB proven; +31.46MB pre-split region when WPRE)
    u16* h1H = (u16*)(W + 0);          u16* h1L = (u16*)(W + 16777216);
    u16* h2H = (u16*)(W + 33554432);   u16* h2L = (u16*)(W + 50331648);
    u16* r2H = (u16*)(W + 67108864);   u16* r2L = (u16*)(W + 83886080);
    u16* r1H = h1H;                    u16* r1L = h1L;
    u16* latH = h1H;                   u16* latL = h1L;
    u16* xPH  = (u16*)(W + 67108864);  u16* xPL  = (u16*)(W + 73400320);
    u16* w1PH = (u16*)(W + 79691776);  u16* w1PL = (u16*)(W + 79986688);
    u16* w2PH = (u16*)(W + 80281600);  u16* w2PL = (u16*)(W + 83427328);
    u16* cbTH = (u16*)(W + 67108864);  u16* cbTL = (u16*)(W + 75497472);
    float* CN = (float*)(W + 83886080);
    float* PV = (float*)(W + 83918848);
    int*   PI = (int*)(W + 88113152);
    const bool WPRE = ws_size >= (size_t)132120576;
    u16* raPH = (u16*)(W + 100663296); u16* raPL = (u16*)(W + 106954752);
    u16* rbPH = (u16*)(W + 113246208); u16* rbPL = (u16*)(W + 119537664);
    u16* rcPH = (u16*)(W + 125829120); u16* rcPL = (u16*)(W + 127926272);
    u16* wfPH = (u16*)(W + 130023424); u16* wfPL = (u16*)(W + 131072000);

    prep_x<<<BATCH * T_IN / 256, 256, 0, stream>>>(x, xPH, xPL);
    prep_w<<<(HID1 * 96 + 255) / 256, 256, 0, stream>>>(w1, w1PH, w1PL, HID1, 80, 96, 3);
    prep_w<<<(HID2 * HID1 + 255) / 256, 256, 0, stream>>>(w2, w2PH, w2PL, HID2, HID1, HID1, 3);

    if (WPRE) {
        // conv1: BM=64 (stride-2 SPAN fits LDS), grid 256mt x 4nt
        conv_mfma2<3, 2, 32, true, false><<<1024, 256, 0, stream>>>(
            xPH, xPL, w1PH, w1PL, b1, nullptr, nullptr, h1H, h1L, 96, HID1, T_IN, T1, 4);
        // conv2: BM=64, grid 128mt x 8nt
        conv_mfma2<3, 2, 32, true, false><<<1024, 256, 0, stream>>>(
            h1H, h1L, w2PH, w2PL, b2, nullptr, nullptr, h2H, h2L, HID1, HID2, T1, T2, 8);
        for (int i = 0; i < N_RES; ++i) {
            prep_w<<<(HID2 * HID2 + 255) / 256, 256, 0, stream>>>(
                rwa + (size_t)i * 3145728, raPH, raPL, HID2, HID2, HID2, 3);
            prep_w<<<(HID2 * HID2 + 255) / 256, 256, 0, stream>>>(
                rwb + (size_t)i * 3145728, rbPH, rbPL, HID2, HID2, HID2, 3);
            prep_w<<<(HID2 * HID2 + 255) / 256, 256, 0, stream>>>(
                rwc + (size_t)i * 1048576, rcPH, rcPL, HID2, HID2, HID2, 1);
            conv_mfma2<3, 1, 64, true, false><<<512, 256, 0, stream>>>(
                h2H, h2L, raPH, raPL, rba + (size_t)i * HID2, nullptr, nullptr,
                r1H, r1L, HID2, HID2, T2, T2, 8);
            conv_mfma2<3, 1, 64, true, false><<<512, 256, 0, stream>>>(
                r1H, r1L, rbPH, rbPL, rbb + (size_t)i * HID2, nullptr, nullptr,
                r2H, r2L, HID2, HID2, T2, T2, 8);
            conv_mfma2<1, 1, 64, false, true><<<512, 256, 0, stream>>>(
                r2H, r2L, rcPH, rcPL, rbc + (size_t)i * HID2, h2H, h2L,
                h2H, h2L, HID2, HID2, T2, T2, 8);
        }
        prep_w<<<(CODE_DIM * HID2 + 255) / 256, 256, 0, stream>>>(wf, wfPH, wfPL, CODE_DIM, HID2, HID2, 1);
        conv_mfma2<1, 1, 32, false, false><<<512, 256, 0, stream>>>(
            h2H, h2L, wfPH, wfPL, bf, nullptr, nullptr, latH, latL,
            HID2, CODE_DIM, T2, T2, 4);
    } else {
        // fallback = round-4 proven path
        conv_mfma<3, 2, 64, true, true, false><<<512, 256, 0, stream>>>(
            xPH, xPL, nullptr, w1PH, w1PL, b1, nullptr, nullptr, h1H, h1L,
            96, HID1, T_IN, T1, 4);
        conv_mfma<3, 2, 64, true, true, false><<<512, 256, 0, stream>>>(
            h1H, h1L, nullptr, w2PH, w2PL, b2, nullptr, nullptr, h2H, h2L,
            HID1, HID2, T1, T2, 8);
        for (int i = 0; i < N_RES; ++i) {
            const float* wa = rwa + (size_t)i * HID2 * HID2 * 3;
            const float* wb = rwb + (size_t)i * HID2 * HID2 * 3;
            const float* wc = rwc + (size_t)i * HID2 * HID2;
            conv_mfma<3, 1, 64, false, true, false><<<512, 256, 0, stream>>>(
                h2H, h2L, wa, nullptr, nullptr, rba + (size_t)i * HID2, nullptr, nullptr,
                r1H, r1L, HID2, HID2, T2, T2, 8);
            conv_mfma<3, 1, 64, false, true, false><<<512, 256, 0, stream>>>(
                r1H, r1L, wb, nullptr, nullptr, rbb + (size_t)i * HID2, nullptr, nullptr,
                r2H, r2L, HID2, HID2, T2, T2, 8);
            conv_mfma<1, 1, 64, false, false, true><<<512, 256, 0, stream>>>(
                r2H, r2L, wc, nullptr, nullptr, rbc + (size_t)i * HID2, h2H, h2L,
                h2H, h2L, HID2, HID2, T2, T2, 8);
        }
        conv_mfma<1, 1, 32, false, false, false><<<512, 256, 0, stream>>>(
            h2H, h2L, wf, nullptr, nullptr, bf, nullptr, nullptr, latH, latL,
            HID2, CODE_DIM, T2, T2, 4);
    }

    // VQ argmin
    prep_cb<<<dim3(N_TOK / 32, CODE_DIM / 32), 256, 0, stream>>>(cb, cbTH, cbTL);
    cnorm_kernel<<<N_TOK / 256, 256, 0, stream>>>(cb, CN);
    vq_mfma<<<dim3(N_ROWS / 256, N_TOK / 128), 256, 0, stream>>>(latH, latL, cbTH, cbTL, CN, PV, PI);
    vq_merge<<<N_ROWS / 256, 256, 0, stream>>>(PV, PI, (int*)d_out);
}

// Round 7
// 1826.637 us; speedup vs baseline: 2.1237x; 2.1237x over previous
//
#include <hip/hip_runtime.h>
#include <cstdint>

// ---------------------------------------------------------------------------
#define BATCH   16
#define T_IN    2048
#define HID1    512
#define HID2    1024
#define T1      1024
#define T2      512
#define CODE_DIM 512
#define N_TOK   8192
#define N_RES   3
#define N_ROWS  (BATCH * T2)

typedef short bf16x8 __attribute__((ext_vector_type(8)));
typedef float f32x4  __attribute__((ext_vector_type(4)));
typedef unsigned short u16;

union B128 { int4 i; bf16x8 b; };

// bf16x2 split: u32 = hi_bits | (lo_bits << 16); v ~= bf16(hi) + bf16(lo)
__device__ __forceinline__ unsigned splitpack(float v) {
    unsigned r  = __float_as_uint(v);
    unsigned hi = (r + 0x7FFFu + ((r >> 16) & 1u)) >> 16;
    float    res = v - __uint_as_float(hi << 16);
    unsigned rl = __float_as_uint(res);
    unsigned lo = (rl + 0x7FFFu + ((rl >> 16) & 1u)) >> 16;
    return hi | (lo << 16);
}
__device__ __forceinline__ float bf2f(u16 b) { return __uint_as_float(((unsigned)b) << 16); }
__device__ __forceinline__ int swz(int row) { return (row ^ (row >> 2)) & 3; }

// ---------------------------------------------------------------------------
// Round-6 conv: merged-tap staging + T14 reg-prefetch in NAMED SCALARS
// (round-5's lambda-captured arrays were demoted to scratch -> 1.6GB/dispatch
// of spill traffic; named int4 scalars guarantee register allocation).
// Block BM=2*WR rows x BN=128 cols, 4 waves 2x2, wave tile WR x 64.
// Per c0 (K=32): [barrier; ds_write prefetched regs; barrier; issue loads for
// next c0 (clamped, unconditional); setprio(1); MFMA over taps; setprio(0)].
// ---------------------------------------------------------------------------
template<int TAPS, int S, int WR, bool RELU, bool ADD>
__global__ __launch_bounds__(256, 2)
void conv_mfma3(const u16* __restrict__ xH, const u16* __restrict__ xL,
                const u16* __restrict__ wHp, const u16* __restrict__ wLp,
                const float* __restrict__ bias,
                const u16* __restrict__ addH, const u16* __restrict__ addL,
                u16* __restrict__ oH, u16* __restrict__ oL,
                int Cin, int Cout, int Tin, int Tout, int ntc)
{
    constexpr int BM = WR * 2, BN = 128;
    constexpr int PAD  = (TAPS == 3) ? 1 : 0;
    constexpr int SPAN = BM * S + TAPS - S;
    constexpr int MF   = WR / 16;
    static_assert(SPAN <= 256, "one staged row per thread");

    __shared__ int4 sXh[SPAN][4], sXl[SPAN][4];
    __shared__ int4 sWh[TAPS][BN][4], sWl[TAPS][BN][4];

    const int tid  = threadIdx.x;
    const int lane = tid & 63, wid = tid >> 6;
    const int wm = wid >> 1, wn = wid & 1;
    const int l15 = lane & 15, l4 = lane >> 4;

    const int bid = blockIdx.x;
    const int nt = bid % ntc, mt = bid / ntc;   // same-nt blocks cluster on XCD (rr)
    const int R0 = mt * BM, o0 = nt * BN;
    const int b  = R0 / Tout, t0 = R0 % Tout;
    const int tbase = t0 * S - PAD;

    // X prefetch source (invalid rows -> safe row 0, zeroed at store)
    const int  xt = tbase + tid;
    const bool xv = (tid < SPAN) && (xt >= 0) && (xt < Tin);
    const u16* xpH = xH + ((size_t)b * Tin + (xv ? xt : 0)) * Cin;
    const u16* xpL = xL + ((size_t)b * Tin + (xv ? xt : 0)) * Cin;
    // W prefetch source
    const int wrow = tid >> 1, whalf = tid & 1;
    const size_t wstep = (size_t)Cout * Cin;
    const u16* wpH = wHp + (size_t)(o0 + wrow) * Cin + whalf * 16;
    const u16* wpL = wLp + (size_t)(o0 + wrow) * Cin + whalf * 16;

    f32x4 acc[MF][4] = {};

    // named-scalar prefetch state (NO arrays, NO lambdas)
    int4 x0h, x1h, x2h, x3h, x0l, x1l, x2l, x3l;
    int4 wa0, wa1, wa2, wa3;
    int4 wb0 = {}, wb1 = {}, wb2 = {}, wb3 = {};
    int4 wc0 = {}, wc1 = {}, wc2 = {}, wc3 = {};

#define CONV_LOAD(c0)  do {                                                    \
    { const int4* pH = (const int4*)(xpH + (c0));                              \
      const int4* pL = (const int4*)(xpL + (c0));                              \
      x0h = pH[0]; x1h = pH[1]; x2h = pH[2]; x3h = pH[3];                      \
      x0l = pL[0]; x1l = pL[1]; x2l = pL[2]; x3l = pL[3]; }                    \
    { const int4* qH = (const int4*)(wpH + (c0));                              \
      const int4* qL = (const int4*)(wpL + (c0));                              \
      wa0 = qH[0]; wa1 = qH[1]; wa2 = qL[0]; wa3 = qL[1]; }                    \
    if constexpr (TAPS == 3) {                                                 \
      { const int4* qH = (const int4*)(wpH + wstep + (c0));                    \
        const int4* qL = (const int4*)(wpL + wstep + (c0));                    \
        wb0 = qH[0]; wb1 = qH[1]; wb2 = qL[0]; wb3 = qL[1]; }                  \
      { const int4* qH = (const int4*)(wpH + 2 * wstep + (c0));                \
        const int4* qL = (const int4*)(wpL + 2 * wstep + (c0));                \
        wc0 = qH[0]; wc1 = qH[1]; wc2 = qL[0]; wc3 = qL[1]; } } } while (0)

#define CONV_STORE()  do {                                                     \
    if (tid < SPAN) {                                                          \
        const int s = swz(tid);                                                \
        if (xv) {                                                              \
            sXh[tid][0 ^ s] = x0h; sXh[tid][1 ^ s] = x1h;                      \
            sXh[tid][2 ^ s] = x2h; sXh[tid][3 ^ s] = x3h;                      \
            sXl[tid][0 ^ s] = x0l; sXl[tid][1 ^ s] = x1l;                      \
            sXl[tid][2 ^ s] = x2l; sXl[tid][3 ^ s] = x3l;                      \
        } else {                                                               \
            const int4 z = {0, 0, 0, 0};                                       \
            sXh[tid][0] = z; sXh[tid][1] = z; sXh[tid][2] = z; sXh[tid][3] = z; \
            sXl[tid][0] = z; sXl[tid][1] = z; sXl[tid][2] = z; sXl[tid][3] = z; \
        }                                                                      \
    }                                                                          \
    { const int s2 = swz(wrow);                                                \
      sWh[0][wrow][(whalf * 2 + 0) ^ s2] = wa0;                                \
      sWh[0][wrow][(whalf * 2 + 1) ^ s2] = wa1;                                \
      sWl[0][wrow][(whalf * 2 + 0) ^ s2] = wa2;                                \
      sWl[0][wrow][(whalf * 2 + 1) ^ s2] = wa3;                                \
      if constexpr (TAPS == 3) {                                               \
        sWh[1][wrow][(whalf * 2 + 0) ^ s2] = wb0;                              \
        sWh[1][wrow][(whalf * 2 + 1) ^ s2] = wb1;                              \
        sWl[1][wrow][(whalf * 2 + 0) ^ s2] = wb2;                              \
        sWl[1][wrow][(whalf * 2 + 1) ^ s2] = wb3;                              \
        sWh[2][wrow][(whalf * 2 + 0) ^ s2] = wc0;                              \
        sWh[2][wrow][(whalf * 2 + 1) ^ s2] = wc1;                              \
        sWl[2][wrow][(whalf * 2 + 0) ^ s2] = wc2;                              \
        sWl[2][wrow][(whalf * 2 + 1) ^ s2] = wc3; } } } while (0)

    CONV_LOAD(0);
    for (int c0 = 0; c0 < Cin; c0 += 32) {
        __syncthreads();              // previous MFMA phase done reading LDS
        CONV_STORE();
        __syncthreads();
        const int cn = (c0 + 32 < Cin) ? c0 + 32 : c0;   // clamped, branchless
        CONV_LOAD(cn);                // in flight under the MFMA phase (T14)

        __builtin_amdgcn_s_setprio(1);
#pragma unroll
        for (int tap = 0; tap < TAPS; ++tap) {
            B128 bh[4], bl[4];
#pragma unroll
            for (int nf = 0; nf < 4; ++nf) {
                const int orow = wn * 64 + nf * 16 + l15;
                const int sl = l4 ^ swz(orow);
                bh[nf].i = sWh[tap][orow][sl];
                bl[nf].i = sWl[tap][orow][sl];
            }
#pragma unroll
            for (int mf = 0; mf < MF; ++mf) {
                const int r = (wm * WR + mf * 16 + l15) * S + tap;
                const int sl = l4 ^ swz(r);
                B128 ah, al;
                ah.i = sXh[r][sl];  al.i = sXl[r][sl];
#pragma unroll
                for (int nf = 0; nf < 4; ++nf) {
                    acc[mf][nf] = __builtin_amdgcn_mfma_f32_16x16x32_bf16(ah.b, bh[nf].b, acc[mf][nf], 0, 0, 0);
                    acc[mf][nf] = __builtin_amdgcn_mfma_f32_16x16x32_bf16(ah.b, bl[nf].b, acc[mf][nf], 0, 0, 0);
                    acc[mf][nf] = __builtin_amdgcn_mfma_f32_16x16x32_bf16(al.b, bh[nf].b, acc[mf][nf], 0, 0, 0);
                }
            }
        }
        __builtin_amdgcn_s_setprio(0);
    }
#undef CONV_LOAD
#undef CONV_STORE

    // epilogue: D row=(l>>4)*4+rg (t), col=l&15 (o)
#pragma unroll
    for (int nf = 0; nf < 4; ++nf) {
        const int o = o0 + wn * 64 + nf * 16 + l15;
        const float bv = bias[o];
#pragma unroll
        for (int mf = 0; mf < MF; ++mf) {
#pragma unroll
            for (int rg = 0; rg < 4; ++rg) {
                const int Rl = wm * WR + mf * 16 + l4 * 4 + rg;
                const size_t idx = (size_t)(R0 + Rl) * Cout + o;
                float v = acc[mf][nf][rg] + bv;
                if constexpr (ADD)  v += bf2f(addH[idx]) + bf2f(addL[idx]);
                if constexpr (RELU) v = fmaxf(v, 0.f);
                const unsigned p = splitpack(v);
                oH[idx] = (u16)(p & 0xFFFFu);
                oL[idx] = (u16)(p >> 16);
            }
        }
    }
}

// ---------------------------------------------------------------------------
// Round-4 conv kernel, kept VERBATIM as the ws-too-small fallback path.
// ---------------------------------------------------------------------------
template<int TAPS, int S, int WR, bool WPRE, bool RELU, bool ADD>
__global__ __launch_bounds__(256, 2)
void conv_mfma(const u16* __restrict__ xH, const u16* __restrict__ xL,
               const float* __restrict__ wraw,
               const u16* __restrict__ wHp, const u16* __restrict__ wLp,
               const float* __restrict__ bias,
               const u16* __restrict__ addH, const u16* __restrict__ addL,
               u16* __restrict__ oH, u16* __restrict__ oL,
               int Cin, int Cout, int Tin, int Tout, int ntc)
{
    constexpr int BM = WR * 2, BN = 128;
    constexpr int PAD  = (TAPS == 3) ? 1 : 0;
    constexpr int SPAN = BM * S + TAPS - S;
    constexpr int MF   = WR / 16;

    __shared__ int4 sXh[SPAN][4], sXl[SPAN][4];
    __shared__ int4 sWh[BN][4],  sWl[BN][4];

    const int tid  = threadIdx.x;
    const int lane = tid & 63, wid = tid >> 6;
    const int wm = wid >> 1, wn = wid & 1;
    const int l15 = lane & 15, l4 = lane >> 4;

    const int bid = blockIdx.x;
    const int nt = bid % ntc, mt = bid / ntc;
    const int R0 = mt * BM, o0 = nt * BN;
    const int b  = R0 / Tout, t0 = R0 % Tout;
    const int tbase = t0 * S - PAD;

    f32x4 acc[MF][4] = {};

    const u16* bxH = xH + (size_t)b * Tin * Cin;
    const u16* bxL = xL + (size_t)b * Tin * Cin;

    for (int c0 = 0; c0 < Cin; c0 += 32) {
        for (int tap = 0; tap < TAPS; ++tap) {
            __syncthreads();
            if (tap == 0) {
                for (int r = tid; r < SPAN; r += 256) {
                    const int t = tbase + r;
                    const int s = swz(r);
                    if (t >= 0 && t < Tin) {
                        const int4* pH = (const int4*)(bxH + (size_t)t * Cin + c0);
                        const int4* pL = (const int4*)(bxL + (size_t)t * Cin + c0);
#pragma unroll
                        for (int j = 0; j < 4; ++j) sXh[r][j ^ s] = pH[j];
#pragma unroll
                        for (int j = 0; j < 4; ++j) sXl[r][j ^ s] = pL[j];
                    } else {
                        const int4 z = {0, 0, 0, 0};
#pragma unroll
                        for (int j = 0; j < 4; ++j) { sXh[r][j] = z; sXl[r][j] = z; }
                    }
                }
            }
            if constexpr (WPRE) {
                const int row = tid & 127, half = tid >> 7;
                const int s = swz(row);
                const size_t base = ((size_t)tap * Cout + (o0 + row)) * Cin + c0 + half * 16;
                const int4* pH = (const int4*)(wHp + base);
                const int4* pL = (const int4*)(wLp + base);
                sWh[row][(half * 2 + 0) ^ s] = pH[0];
                sWh[row][(half * 2 + 1) ^ s] = pH[1];
                sWl[row][(half * 2 + 0) ^ s] = pL[0];
                sWl[row][(half * 2 + 1) ^ s] = pL[1];
            } else {
                const int row = tid >> 1, half = tid & 1;
                const int s = swz(row);
                const float* wp = wraw + ((size_t)(o0 + row) * Cin + (c0 + half * 16)) * TAPS + tap;
                unsigned p[16];
#pragma unroll
                for (int j = 0; j < 16; ++j) p[j] = splitpack(wp[(size_t)j * TAPS]);
                int4 h0, h1, l0, l1;
                h0.x = (int)((p[0]&0xFFFFu)|(p[1]<<16));   h0.y = (int)((p[2]&0xFFFFu)|(p[3]<<16));
                h0.z = (int)((p[4]&0xFFFFu)|(p[5]<<16));   h0.w = (int)((p[6]&0xFFFFu)|(p[7]<<16));
                h1.x = (int)((p[8]&0xFFFFu)|(p[9]<<16));   h1.y = (int)((p[10]&0xFFFFu)|(p[11]<<16));
                h1.z = (int)((p[12]&0xFFFFu)|(p[13]<<16)); h1.w = (int)((p[14]&0xFFFFu)|(p[15]<<16));
                l0.x = (int)((p[0]>>16)|(p[1]&0xFFFF0000u));   l0.y = (int)((p[2]>>16)|(p[3]&0xFFFF0000u));
                l0.z = (int)((p[4]>>16)|(p[5]&0xFFFF0000u));   l0.w = (int)((p[6]>>16)|(p[7]&0xFFFF0000u));
                l1.x = (int)((p[8]>>16)|(p[9]&0xFFFF0000u));   l1.y = (int)((p[10]>>16)|(p[11]&0xFFFF0000u));
                l1.z = (int)((p[12]>>16)|(p[13]&0xFFFF0000u)); l1.w = (int)((p[14]>>16)|(p[15]&0xFFFF0000u));
                sWh[row][(half * 2 + 0) ^ s] = h0;  sWh[row][(half * 2 + 1) ^ s] = h1;
                sWl[row][(half * 2 + 0) ^ s] = l0;  sWl[row][(half * 2 + 1) ^ s] = l1;
            }
            __syncthreads();

            B128 bh[4], bl[4];
#pragma unroll
            for (int nf = 0; nf < 4; ++nf) {
                const int orow = wn * 64 + nf * 16 + l15;
                const int sl = l4 ^ swz(orow);
                bh[nf].i = sWh[orow][sl];  bl[nf].i = sWl[orow][sl];
            }
#pragma unroll
            for (int mf = 0; mf < MF; ++mf) {
                const int r = (wm * WR + mf * 16 + l15) * S + tap;
                const int sl = l4 ^ swz(r);
                B128 ah, al;
                ah.i = sXh[r][sl];  al.i = sXl[r][sl];
#pragma unroll
                for (int nf = 0; nf < 4; ++nf) {
                    acc[mf][nf] = __builtin_amdgcn_mfma_f32_16x16x32_bf16(ah.b, bh[nf].b, acc[mf][nf], 0, 0, 0);
                    acc[mf][nf] = __builtin_amdgcn_mfma_f32_16x16x32_bf16(ah.b, bl[nf].b, acc[mf][nf], 0, 0, 0);
                    acc[mf][nf] = __builtin_amdgcn_mfma_f32_16x16x32_bf16(al.b, bh[nf].b, acc[mf][nf], 0, 0, 0);
                }
            }
        }
    }

#pragma unroll
    for (int nf = 0; nf < 4; ++nf) {
        const int o = o0 + wn * 64 + nf * 16 + l15;
        const float bv = bias[o];
#pragma unroll
        for (int mf = 0; mf < MF; ++mf) {
#pragma unroll
            for (int rg = 0; rg < 4; ++rg) {
                const int Rl = wm * WR + mf * 16 + l4 * 4 + rg;
                const size_t idx = (size_t)(R0 + Rl) * Cout + o;
                float v = acc[mf][nf][rg] + bv;
                if constexpr (ADD)  v += bf2f(addH[idx]) + bf2f(addL[idx]);
                if constexpr (RELU) v = fmaxf(v, 0.f);
                const unsigned p = splitpack(v);
                oH[idx] = (u16)(p & 0xFFFFu);
                oL[idx] = (u16)(p >> 16);
            }
        }
    }
}

// ---------------------------------------------------------------------------
// Prep kernels
// ---------------------------------------------------------------------------
__global__ void prep_x(const float* __restrict__ x, u16* __restrict__ xH, u16* __restrict__ xL)
{
    const int id = blockIdx.x * 256 + threadIdx.x;     // (b,t)
    const int b = id >> 11, t = id & 2047;
    const float* src = x + (size_t)b * 80 * 2048 + t;
    u16* dH = xH + (size_t)id * 96;
    u16* dL = xL + (size_t)id * 96;
    for (int c = 0; c < 96; ++c) {
        const float v = (c < 80) ? src[(size_t)c * 2048] : 0.f;
        const unsigned p = splitpack(v);
        dH[c] = (u16)(p & 0xFFFFu);
        dL[c] = (u16)(p >> 16);
    }
}

// w fp32 [O][CinR][TAPS] -> planes [TAPS][O][CinP] (c >= CinR zero-padded)
__global__ void prep_w(const float* __restrict__ w, u16* __restrict__ wH, u16* __restrict__ wL,
                       int O, int CinR, int CinP, int TAPS)
{
    const int id = blockIdx.x * 256 + threadIdx.x;     // (o, c) over CinP
    if (id >= O * CinP) return;
    const int o = id / CinP, c = id % CinP;
    for (int t = 0; t < TAPS; ++t) {
        const float v = (c < CinR) ? w[((size_t)o * CinR + c) * TAPS + t] : 0.f;
        const unsigned p = splitpack(v);
        const size_t dst = ((size_t)t * O + o) * CinP + c;
        wH[dst] = (u16)(p & 0xFFFFu);
        wL[dst] = (u16)(p >> 16);
    }
}

__global__ void prep_cb(const float* __restrict__ cb, u16* __restrict__ cH, u16* __restrict__ cL)
{
    __shared__ float tile[32][33];
    const int jb = blockIdx.x * 32, db = blockIdx.y * 32;
    const int c = threadIdx.x & 31, r = threadIdx.x >> 5;
    for (int rr = r; rr < 32; rr += 8)
        tile[rr][c] = cb[(size_t)(db + rr) * N_TOK + jb + c];
    __syncthreads();
    for (int rr = r; rr < 32; rr += 8) {
        const unsigned p = splitpack(tile[c][rr]);
        const size_t dst = (size_t)(jb + rr) * CODE_DIM + db + c;
        cH[dst] = (u16)(p & 0xFFFFu);
        cL[dst] = (u16)(p >> 16);
    }
}

__global__ void cnorm_kernel(const float* __restrict__ cb, float* __restrict__ cnorm)
{
    const int j = blockIdx.x * 256 + threadIdx.x;
    float s = 0.f;
#pragma unroll 8
    for (int d = 0; d < CODE_DIM; ++d) {
        const float v = cb[(size_t)d * N_TOK + j];
        s += v * v;
    }
    cnorm[j] = s;
}

// ---------------------------------------------------------------------------
// VQ: argmax_j (2*f.c_j - |c_j|^2) via MFMA; named-scalar T14 prefetch.
// Block 256 rows x 128 codes, 4 waves 2x2 (wave 128 rows x 64 codes).
// ---------------------------------------------------------------------------
__global__ __launch_bounds__(256, 2)
void vq_mfma3(const u16* __restrict__ latH, const u16* __restrict__ latL,
              const u16* __restrict__ cbH, const u16* __restrict__ cbL,
              const float* __restrict__ cnorm,
              float* __restrict__ pval, int* __restrict__ pidx)
{
    __shared__ int4 sXh[256][4], sXl[256][4];
    __shared__ int4 sWh[128][4], sWl[128][4];

    const int tid  = threadIdx.x;
    const int lane = tid & 63, wid = tid >> 6;
    const int wm = wid >> 1, wn = wid & 1;
    const int l15 = lane & 15, l4 = lane >> 4;
    const int R0 = blockIdx.x * 256;
    const int o0 = blockIdx.y * 128;

    f32x4 acc[8][4] = {};

    const u16* xrH = latH + (size_t)(R0 + tid) * CODE_DIM;
    const u16* xrL = latL + (size_t)(R0 + tid) * CODE_DIM;
    const int wrow = tid >> 1, whalf = tid & 1;
    const u16* wrH = cbH + (size_t)(o0 + wrow) * CODE_DIM + whalf * 16;
    const u16* wrL = cbL + (size_t)(o0 + wrow) * CODE_DIM + whalf * 16;

    int4 x0h, x1h, x2h, x3h, x0l, x1l, x2l, x3l, w0, w1, w2, w3;

#define VQ_LOAD(c0)  do {                                                      \
    { const int4* pH = (const int4*)(xrH + (c0));                              \
      const int4* pL = (const int4*)(xrL + (c0));                              \
      x0h = pH[0]; x1h = pH[1]; x2h = pH[2]; x3h = pH[3];                      \
      x0l = pL[0]; x1l = pL[1]; x2l = pL[2]; x3l = pL[3]; }                    \
    { const int4* qH = (const int4*)(wrH + (c0));                              \
      const int4* qL = (const int4*)(wrL + (c0));                              \
      w0 = qH[0]; w1 = qH[1]; w2 = qL[0]; w3 = qL[1]; } } while (0)

#define VQ_STORE()  do {                                                       \
    { const int s = swz(tid);                                                  \
      sXh[tid][0 ^ s] = x0h; sXh[tid][1 ^ s] = x1h;                            \
      sXh[tid][2 ^ s] = x2h; sXh[tid][3 ^ s] = x3h;                            \
      sXl[tid][0 ^ s] = x0l; sXl[tid][1 ^ s] = x1l;                            \
      sXl[tid][2 ^ s] = x2l; sXl[tid][3 ^ s] = x3l; }                          \
    { const int s2 = swz(wrow);                                                \
      sWh[wrow][(whalf * 2 + 0) ^ s2] = w0;                                    \
      sWh[wrow][(whalf * 2 + 1) ^ s2] = w1;                                    \
      sWl[wrow][(whalf * 2 + 0) ^ s2] = w2;                                    \
      sWl[wrow][(whalf * 2 + 1) ^ s2] = w3; } } while (0)

    VQ_LOAD(0);
    for (int c0 = 0; c0 < CODE_DIM; c0 += 32) {
        __syncthreads();
        VQ_STORE();
        __syncthreads();
        const int cn = (c0 + 32 < CODE_DIM) ? c0 + 32 : c0;
        VQ_LOAD(cn);

        __builtin_amdgcn_s_setprio(1);
        B128 bh[4], bl[4];
#pragma unroll
        for (int nf = 0; nf < 4; ++nf) {
            const int orow = wn * 64 + nf * 16 + l15;
            const int sl = l4 ^ swz(orow);
            bh[nf].i = sWh[orow][sl];  bl[nf].i = sWl[orow][sl];
        }
#pragma unroll
        for (int mf = 0; mf < 8; ++mf) {
            const int r = wm * 128 + mf * 16 + l15;
            const int sl = l4 ^ swz(r);
            B128 ah, al;
            ah.i = sXh[r][sl];  al.i = sXl[r][sl];
#pragma unroll
            for (int nf = 0; nf < 4; ++nf) {
                acc[mf][nf] = __builtin_amdgcn_mfma_f32_16x16x32_bf16(ah.b, bh[nf].b, acc[mf][nf], 0, 0, 0);
                acc[mf][nf] = __builtin_amdgcn_mfma_f32_16x16x32_bf16(ah.b, bl[nf].b, acc[mf][nf], 0, 0, 0);
                acc[mf][nf] = __builtin_amdgcn_mfma_f32_16x16x32_bf16(al.b, bh[nf].b, acc[mf][nf], 0, 0, 0);
            }
        }
        __builtin_amdgcn_s_setprio(0);
    }
#undef VQ_LOAD
#undef VQ_STORE

    float cn4[4]; int jb4[4];
#pragma unroll
    for (int nf = 0; nf < 4; ++nf) {
        jb4[nf] = o0 + wn * 64 + nf * 16 + l15;
        cn4[nf] = cnorm[jb4[nf]];
    }
    const int slice = blockIdx.y * 2 + wn;
#pragma unroll
    for (int mf = 0; mf < 8; ++mf) {
#pragma unroll
        for (int rg = 0; rg < 4; ++rg) {
            float bv = -3.4e38f; int bj = 0;
#pragma unroll
            for (int nf = 0; nf < 4; ++nf) {      // ascending j: strict > keeps first min
                const float v = 2.f * acc[mf][nf][rg] - cn4[nf];
                if (v > bv) { bv = v; bj = jb4[nf]; }
            }
#pragma unroll
            for (int m = 1; m < 16; m <<= 1) {
                const float ov = __shfl_xor(bv, m, 64);
                const int   oj = __shfl_xor(bj, m, 64);
                if (ov > bv || (ov == bv && oj < bj)) { bv = ov; bj = oj; }
            }
            if (l15 == 0) {
                const int R = R0 + wm * 128 + mf * 16 + l4 * 4 + rg;
                pval[(size_t)slice * N_ROWS + R] = bv;
                pidx[(size_t)slice * N_ROWS + R] = bj;
            }
        }
    }
}

__global__ void vq_merge(const float* __restrict__ pval, const int* __restrict__ pidx,
                         int* __restrict__ out)
{
    const int row = blockIdx.x * 256 + threadIdx.x;
    float bv = pval[row]; int bj = pidx[row];
    for (int s = 1; s < 128; ++s) {
        const float v = pval[(size_t)s * N_ROWS + row];
        const int   j = pidx[(size_t)s * N_ROWS + row];
        if (v > bv || (v == bv && j < bj)) { bv = v; bj = j; }
    }
    out[row] = bj;
}

// ---------------------------------------------------------------------------
// Launch
// ---------------------------------------------------------------------------
extern "C" void kernel_launch(void* const* d_in, const int* in_sizes, int n_in,
                              void* d_out, int out_size, void* d_ws, size_t ws_size,
                              hipStream_t stream)
{
    const float* x   = (const float*)d_in[0];
    const float* w1  = (const float*)d_in[1];
    const float* b1  = (const float*)d_in[2];
    const float* w2  = (const float*)d_in[3];
    const float* b2  = (const float*)d_in[4];
    const float* rwa = (const float*)d_in[5];
    const float* rba = (const float*)d_in[6];
    const float* rwb = (const float*)d_in[7];
    const float* rbb = (const float*)d_in[8];
    const float* rwc = (const float*)d_in[9];
    const float* rbc = (const float*)d_in[10];
    const float* wf  = (const float*)d_in[11];
    const float* bf  = (const float*)d_in[12];
    const float* cb  = (const float*)d_in[13];

    char* W = (char*)d_ws;
    // byte layout (base 100.66MB proven; +31.46MB pre-split region when WPRE)
    u16* h1H = (u16*)(W + 0);          u16* h1L = (u16*)(W + 16777216);
    u16* h2H = (u16*)(W + 33554432);   u16* h2L = (u16*)(W + 50331648);
    u16* r2H = (u16*)(W + 67108864);   u16* r2L = (u16*)(W + 83886080);
    u16* r1H = h1H;                    u16* r1L = h1L;
    u16* latH = h1H;                   u16* latL = h1L;
    u16* xPH  = (u16*)(W + 67108864);  u16* xPL  = (u16*)(W + 73400320);
    u16* w1PH = (u16*)(W + 79691776);  u16* w1PL = (u16*)(W + 79986688);
    u16* w2PH = (u16*)(W + 80281600);  u16* w2PL = (u16*)(W + 83427328);
    u16* cbTH = (u16*)(W + 67108864);  u16* cbTL = (u16*)(W + 75497472);
    float* CN = (float*)(W + 83886080);
    float* PV = (float*)(W + 83918848);
    int*   PI = (int*)(W + 88113152);
    const bool WPRE = ws_size >= (size_t)132120576;
    u16* raPH = (u16*)(W + 100663296); u16* raPL = (u16*)(W + 106954752);
    u16* rbPH = (u16*)(W + 113246208); u16* rbPL = (u16*)(W + 119537664);
    u16* rcPH = (u16*)(W + 125829120); u16* rcPL = (u16*)(W + 127926272);
    u16* wfPH = (u16*)(W + 130023424); u16* wfPL = (u16*)(W + 131072000);

    prep_x<<<BATCH * T_IN / 256, 256, 0, stream>>>(x, xPH, xPL);
    prep_w<<<(HID1 * 96 + 255) / 256, 256, 0, stream>>>(w1, w1PH, w1PL, HID1, 80, 96, 3);
    prep_w<<<(HID2 * HID1 + 255) / 256, 256, 0, stream>>>(w2, w2PH, w2PL, HID2, HID1, HID1, 3);

    if (WPRE) {
        conv_mfma3<3, 2, 32, true, false><<<1024, 256, 0, stream>>>(
            xPH, xPL, w1PH, w1PL, b1, nullptr, nullptr, h1H, h1L, 96, HID1, T_IN, T1, 4);
        conv_mfma3<3, 2, 32, true, false><<<1024, 256, 0, stream>>>(
            h1H, h1L, w2PH, w2PL, b2, nullptr, nullptr, h2H, h2L, HID1, HID2, T1, T2, 8);
        for (int i = 0; i < N_RES; ++i) {
            prep_w<<<(HID2 * HID2 + 255) / 256, 256, 0, stream>>>(
                rwa + (size_t)i * 3145728, raPH, raPL, HID2, HID2, HID2, 3);
            prep_w<<<(HID2 * HID2 + 255) / 256, 256, 0, stream>>>(
                rwb + (size_t)i * 3145728, rbPH, rbPL, HID2, HID2, HID2, 3);
            prep_w<<<(HID2 * HID2 + 255) / 256, 256, 0, stream>>>(
                rwc + (size_t)i * 1048576, rcPH, rcPL, HID2, HID2, HID2, 1);
            conv_mfma3<3, 1, 64, true, false><<<512, 256, 0, stream>>>(
                h2H, h2L, raPH, raPL, rba + (size_t)i * HID2, nullptr, nullptr,
                r1H, r1L, HID2, HID2, T2, T2, 8);
            conv_mfma3<3, 1, 64, true, false><<<512, 256, 0, stream>>>(
                r1H, r1L, rbPH, rbPL, rbb + (size_t)i * HID2, nullptr, nullptr,
                r2H, r2L, HID2, HID2, T2, T2, 8);
            conv_mfma3<1, 1, 64, false, true><<<512, 256, 0, stream>>>(
                r2H, r2L, rcPH, rcPL, rbc + (size_t)i * HID2, h2H, h2L,
                h2H, h2L, HID2, HID2, T2, T2, 8);
        }
        prep_w<<<(CODE_DIM * HID2 + 255) / 256, 256, 0, stream>>>(wf, wfPH, wfPL, CODE_DIM, HID2, HID2, 1);
        conv_mfma3<1, 1, 32, false, false><<<512, 256, 0, stream>>>(
            h2H, h2L, wfPH, wfPL, bf, nullptr, nullptr, latH, latL,
            HID2, CODE_DIM, T2, T2, 4);
    } else {
        // fallback = round-4 proven path
        conv_mfma<3, 2, 64, true, true, false><<<512, 256, 0, stream>>>(
            xPH, xPL, nullptr, w1PH, w1PL, b1, nullptr, nullptr, h1H, h1L,
            96, HID1, T_IN, T1, 4);
        conv_mfma<3, 2, 64, true, true, false><<<512, 256, 0, stream>>>(
            h1H, h1L, nullptr, w2PH, w2PL, b2, nullptr, nullptr, h2H, h2L,
            HID1, HID2, T1, T2, 8);
        for (int i = 0; i < N_RES; ++i) {
            const float* wa = rwa + (size_t)i * HID2 * HID2 * 3;
            const float* wb = rwb + (size_t)i * HID2 * HID2 * 3;
            const float* wc = rwc + (size_t)i * HID2 * HID2;
            conv_mfma<3, 1, 64, false, true, false><<<512, 256, 0, stream>>>(
                h2H, h2L, wa, nullptr, nullptr, rba + (size_t)i * HID2, nullptr, nullptr,
                r1H, r1L, HID2, HID2, T2, T2, 8);
            conv_mfma<3, 1, 64, false, true, false><<<512, 256, 0, stream>>>(
                r1H, r1L, wb, nullptr, nullptr, rbb + (size_t)i * HID2, nullptr, nullptr,
                r2H, r2L, HID2, HID2, T2, T2, 8);
            conv_mfma<1, 1, 64, false, false, true><<<512, 256, 0, stream>>>(
                r2H, r2L, wc, nullptr, nullptr, rbc + (size_t)i * HID2, h2H, h2L,
                h2H, h2L, HID2, HID2, T2, T2, 8);
        }
        conv_mfma<1, 1, 32, false, false, false><<<512, 256, 0, stream>>>(
            h2H, h2L, wf, nullptr, nullptr, bf, nullptr, nullptr, latH, latL,
            HID2, CODE_DIM, T2, T2, 4);
    }

    // VQ argmin
    prep_cb<<<dim3(N_TOK / 32, CODE_DIM / 32), 256, 0, stream>>>(cb, cbTH, cbTL);
    cnorm_kernel<<<N_TOK / 256, 256, 0, stream>>>(cb, CN);
    vq_mfma3<<<dim3(N_ROWS / 256, N_TOK / 128), 256, 0, stream>>>(latH, latL, cbTH, cbTL, CN, PV, PI);
    vq_merge<<<N_ROWS / 256, 256, 0, stream>>>(PV, PI, (int*)d_out);
}